// Round 3
// baseline (528.539 us; speedup 1.0000x reference)
//
#include <hip/hip_runtime.h>
#include <math.h>

constexpr int B_ = 4;
constexpr int N_ = 16384;
constexpr int DIN = 256;
constexpr int DOUT = 512;
constexpr int R_ = B_ * N_;   // 65536

typedef __attribute__((ext_vector_type(4))) float f32x4;
typedef __attribute__((ext_vector_type(8))) short short8;

// ---------------- workspace layout (float offsets) ----------------
constexpr size_t o_Gq    = 0;         // 256x256 query gram, part 0 (z=4,5)
constexpr size_t o_Gq2   = 65536;     // 256x256 query gram, part 1 (z=6,7)
constexpr size_t o_Gs    = 131072;    // 4 x 256x256 per-batch source grams
constexpr size_t o_uq    = 393216;    // 256 colsum(query)
constexpr size_t o_us    = 393472;    // 4x256 colsum(source_b)
constexpr size_t o_nrm   = 394496;    // [0]=nq2 [1]=nk2
constexpr size_t ZERO_FLOATS = 394498; // atomically accumulated region -> zero each call
constexpr size_t o_Pv    = 394560;    // 4 x (256x512): G_b @ Wv^T
constexpr size_t o_Pk    = 918848;    // 4 x (256x512): G_b @ Wk^T
constexpr size_t o_Pq    = 1443136;   // 256x512: Gq @ Wq^T
constexpr size_t o_wku   = 1574208;   // 4x512
constexpr size_t o_wvu   = 1576256;   // 4x512
constexpr size_t o_kssum = 1578304;   // 4x512
constexpr size_t o_vssum = 1580352;   // 4x512
constexpr size_t o_kv    = 1582400;   // 4x8x64x64 raw K^T V
constexpr size_t o_W1bt  = 1713472;   // bf16: 4 x [512 c][256 k]  (s folded in)
constexpr size_t o_w2bt  = 1975616;   // bf16: 4 x [16 c][256 k]   (rows 8..15 zero)
constexpr size_t o_C1    = 1983808;   // 4x512 fp32
constexpr size_t o_C2    = 1985856;   // 4x8 fp32
constexpr size_t WS_FLOATS = 1985888; // ~7.9 MB

static __device__ __forceinline__ float dot4(float4 a, float4 b) {
  return a.x * b.x + a.y * b.y + a.z * b.z + a.w * b.w;
}

// fp32 -> bf16 bits, round-to-nearest-even
static __device__ __forceinline__ unsigned short f2b(float f) {
  unsigned int u = __float_as_uint(f);
  u = (u + 0x7FFFu + ((u >> 16) & 1u)) >> 16;
  return (unsigned short)u;
}

// LDS swizzle for the gram transpose tile: mixes col low bits AND col high bits
// (write lanes vary only c>>4; read lanes vary c&7 -> both spread across banks)
#define SWZB(c) ((((c) ^ ((c) >> 4)) & 7) << 4)

// ---------------- 1) Grams: G = A^T A (256x256) + colsum, bf16 MFMA ----------------
// grid (32 chunks of 512 rows, 8 z): z<4 -> source batch z ; z>=4 -> query quarter
__global__ __launch_bounds__(512, 2) void gram_k(const float* __restrict__ Xq,
                                                 const float* __restrict__ Xsrc,
                                                 float* __restrict__ ws) {
  const int z = blockIdx.y;
  const float* A;
  float* G;
  float* u;
  if (z < 4) {
    A = Xsrc + (size_t)z * N_ * DIN;
    G = ws + o_Gs + (size_t)z * 65536;
    u = ws + o_us + z * 256;
  } else {
    A = Xq + (size_t)(z - 4) * N_ * DIN;
    G = ws + ((z & 2) ? o_Gq2 : o_Gq);
    u = ws + o_uq;
  }
  const int row0 = blockIdx.x * 512;
  const int tid = threadIdx.x;
  const int lane = tid & 63, wv = tid >> 6;
  const int i0w = (wv >> 1) * 64;       // wave tile: 64 (i) x 128 (j)
  const int j0w = (wv & 1) * 128;
  const int lc = lane & 15;
  const int klb = (lane >> 4) * 16;

  // double-buffered transposed tile: [buf][col][64 rows] bf16, swizzled. 2x32KB.
  __shared__ __align__(16) unsigned short Xt[2 * 256 * 64];
  char* Lb = (char*)Xt;

  const int p = tid >> 4;             // 0..31: row pair within 64-row chunk
  const int colg = (tid & 15) * 16;   // this thread's 16 columns

  float us16[16] = {};
  f32x4 acc[4][8] = {};
  float4 vreg[8];

  const float* Ab0 = A + (size_t)row0 * DIN + colg;

  auto issue = [&](int kb) {
    const float* src = Ab0 + (size_t)(kb * 64 + 2 * p) * DIN;
#pragma unroll
    for (int rw = 0; rw < 2; ++rw)
#pragma unroll
      for (int g = 0; g < 4; ++g)
        vreg[rw * 4 + g] = *(const float4*)(src + (size_t)rw * DIN + g * 4);
  };
  auto commit = [&](int buf) {
    char* dst = Lb + buf * 32768;
#pragma unroll
    for (int g = 0; g < 4; ++g) {
      const float4 v0 = vreg[g], v1 = vreg[4 + g];
      const float a0[4] = {v0.x, v0.y, v0.z, v0.w};
      const float a1[4] = {v1.x, v1.y, v1.z, v1.w};
#pragma unroll
      for (int j = 0; j < 4; ++j) {
        const int c = colg + g * 4 + j;
        us16[g * 4 + j] += a0[j] + a1[j];
        const unsigned int pk =
            (unsigned int)f2b(a0[j]) | ((unsigned int)f2b(a1[j]) << 16);
        *(unsigned int*)(dst + ((c * 128 + p * 4) ^ SWZB(c))) = pk;
      }
    }
  };
  auto compute = [&](int buf) {
    const char* src = Lb + buf * 32768;
#pragma unroll
    for (int ks = 0; ks < 2; ++ks) {
      const int kb2 = ks * 64 + klb;
      short8 a[4];
#pragma unroll
      for (int fi = 0; fi < 4; ++fi) {
        const int cc = i0w + fi * 16 + lc;
        a[fi] = *(const short8*)(src + ((cc * 128 + kb2) ^ SWZB(cc)));
      }
#pragma unroll
      for (int fjh = 0; fjh < 2; ++fjh) {
        short8 b[4];
#pragma unroll
        for (int fj = 0; fj < 4; ++fj) {
          const int cc = j0w + (fjh * 4 + fj) * 16 + lc;
          b[fj] = *(const short8*)(src + ((cc * 128 + kb2) ^ SWZB(cc)));
        }
#pragma unroll
        for (int fi = 0; fi < 4; ++fi)
#pragma unroll
          for (int fj = 0; fj < 4; ++fj)
            acc[fi][fjh * 4 + fj] = __builtin_amdgcn_mfma_f32_16x16x32_bf16(
                a[fi], b[fj], acc[fi][fjh * 4 + fj], 0, 0, 0);
      }
    }
  };

  // pipeline: prefetch k+1 while computing k
  issue(0);
  commit(0);
  __syncthreads();
  for (int kb = 0; kb < 8; ++kb) {
    const int cur = kb & 1;
    if (kb < 7) issue(kb + 1);
    compute(cur);
    if (kb < 7) {
      commit(cur ^ 1);
      __syncthreads();
    }
  }

  // G atomics (rotated start to spread L2-channel contention)
  const int rot = blockIdx.x & 7;
#pragma unroll
  for (int fi = 0; fi < 4; ++fi) {
    const int ib = i0w + fi * 16 + (lane >> 4) * 4;
#pragma unroll
    for (int fj0 = 0; fj0 < 8; ++fj0) {
      const int fj = (fj0 + rot) & 7;
      const int jb = j0w + fj * 16 + lc;
#pragma unroll
      for (int r = 0; r < 4; ++r)
        atomicAdd(&G[(size_t)(ib + r) * DIN + jb], acc[fi][fj][r]);
    }
  }

  // colsum reduce (fp32-exact, accumulated from pre-conversion values)
  __syncthreads();
  float* red = (float*)Xt;
#pragma unroll
  for (int j = 0; j < 4; ++j)
    *(float4*)&red[p * 256 + colg + j * 4] =
        make_float4(us16[j * 4], us16[j * 4 + 1], us16[j * 4 + 2], us16[j * 4 + 3]);
  __syncthreads();
  if (tid < 256) {
    float s = 0.f;
#pragma unroll 8
    for (int pp = 0; pp < 32; ++pp) s += red[pp * 256 + tid];
    atomicAdd(&u[tid], s);
  }
}

// ---------------- 2) P = G @ W^T  (256x512, K=256) ----------------
// grid (8 ctiles, 4 itiles, 9 jobs); job 8 sums Gq + Gq2 on the fly
__global__ __launch_bounds__(256) void p_k(const float* __restrict__ Wq,
                                           const float* __restrict__ Wk,
                                           const float* __restrict__ Wv,
                                           float* __restrict__ ws) {
  const int job = blockIdx.z;
  const float* G;
  const float* G2 = nullptr;
  const float* W;
  float* P;
  if (job < 4) {
    G = ws + o_Gs + (size_t)job * 65536; W = Wv; P = ws + o_Pv + (size_t)job * 131072;
  } else if (job < 8) {
    G = ws + o_Gs + (size_t)(job - 4) * 65536; W = Wk; P = ws + o_Pk + (size_t)(job - 4) * 131072;
  } else {
    G = ws + o_Gq; G2 = ws + o_Gq2; W = Wq; P = ws + o_Pq;
  }
  const int c0 = blockIdx.x * 64, i0 = blockIdx.y * 64;
  __shared__ float Gt[64][68];
  __shared__ float Wt[64][68];
  const int tid = threadIdx.x;
  const int ty = tid >> 4, tx = tid & 15;
  float acc[4][4] = {};
  for (int k0 = 0; k0 < 256; k0 += 64) {
    __syncthreads();
#pragma unroll
    for (int pg = 0; pg < 4; ++pg) {
      const int idx = tid + pg * 256;
      const int row = idx >> 4, jq = (idx & 15) * 4;
      float4 g = *(const float4*)&G[(size_t)(i0 + row) * DIN + k0 + jq];
      if (G2) {
        const float4 h = *(const float4*)&G2[(size_t)(i0 + row) * DIN + k0 + jq];
        g.x += h.x; g.y += h.y; g.z += h.z; g.w += h.w;
      }
      Gt[jq + 0][row] = g.x; Gt[jq + 1][row] = g.y; Gt[jq + 2][row] = g.z; Gt[jq + 3][row] = g.w;
      const float4 w = *(const float4*)&W[(size_t)(c0 + row) * DIN + k0 + jq];
      Wt[jq + 0][row] = w.x; Wt[jq + 1][row] = w.y; Wt[jq + 2][row] = w.z; Wt[jq + 3][row] = w.w;
    }
    __syncthreads();
#pragma unroll
    for (int k = 0; k < 64; ++k) {
      const float4 a = *(const float4*)&Gt[k][ty * 4];
      const float4 bb = *(const float4*)&Wt[k][tx * 4];
      const float av[4] = {a.x, a.y, a.z, a.w};
      const float bv_[4] = {bb.x, bb.y, bb.z, bb.w};
#pragma unroll
      for (int ii = 0; ii < 4; ++ii)
#pragma unroll
        for (int jj = 0; jj < 4; ++jj) acc[ii][jj] += av[ii] * bv_[jj];
    }
  }
#pragma unroll
  for (int ii = 0; ii < 4; ++ii)
    *(float4*)&P[(size_t)(i0 + ty * 4 + ii) * DOUT + c0 + tx * 4] =
        make_float4(acc[ii][0], acc[ii][1], acc[ii][2], acc[ii][3]);
}

// ---------------- 3) small bilinears: wku/wvu, ks_sum/vs_sum, nq2/nk2 ----------------
__global__ __launch_bounds__(256) void s1_k(const float* __restrict__ Wq,
                                            const float* __restrict__ Wk,
                                            const float* __restrict__ Wv,
                                            const float* __restrict__ bq,
                                            const float* __restrict__ bk,
                                            const float* __restrict__ bv,
                                            float* __restrict__ ws) {
  const int tid = threadIdx.x;
  const int c = blockIdx.x * 64 + (tid >> 2);
  const int part = tid & 3;
  const int i0 = part * 64;
  const int job = blockIdx.y;
  __shared__ float red[256];
  float np = 0.f;
  if (job < 4) {
    const int b = job;
    const float* ub = ws + o_us + b * 256;
    const float* wkr = Wk + (size_t)c * 256;
    const float* wvr = Wv + (size_t)c * 256;
    const float* pk = ws + o_Pk + (size_t)b * 131072 + c;
    float dku = 0.f, dvu = 0.f, dpk = 0.f;
#pragma unroll 4
    for (int t = 0; t < 16; ++t) {
      const float4 u4 = *(const float4*)&ub[i0 + t * 4];
      dku += dot4(*(const float4*)&wkr[i0 + t * 4], u4);
      dvu += dot4(*(const float4*)&wvr[i0 + t * 4], u4);
    }
    for (int i = i0; i < i0 + 64; ++i) dpk += wkr[i] * pk[(size_t)i * 512];
    dku += __shfl_down(dku, 2); dku += __shfl_down(dku, 1);
    dvu += __shfl_down(dvu, 2); dvu += __shfl_down(dvu, 1);
    dpk += __shfl_down(dpk, 2); dpk += __shfl_down(dpk, 1);
    if (part == 0) {
      ws[o_wku + b * 512 + c] = dku;
      ws[o_wvu + b * 512 + c] = dvu;
      ws[o_kssum + b * 512 + c] = dku + (float)N_ * bk[c];
      ws[o_vssum + b * 512 + c] = dvu + (float)N_ * bv[c];
      np = dpk + 2.f * bk[c] * dku + (float)N_ * bk[c] * bk[c];
    }
    red[tid] = np;
    __syncthreads();
    for (int s = 128; s > 0; s >>= 1) {
      if (tid < s) red[tid] += red[tid + s];
      __syncthreads();
    }
    if (tid == 0) atomicAdd(&ws[o_nrm + 1], red[0]);
  } else {
    const float* uq = ws + o_uq;
    const float* wqr = Wq + (size_t)c * 256;
    const float* pq = ws + o_Pq + c;
    float dqu = 0.f, dpq = 0.f;
#pragma unroll 4
    for (int t = 0; t < 16; ++t)
      dqu += dot4(*(const float4*)&wqr[i0 + t * 4], *(const float4*)&uq[i0 + t * 4]);
    for (int i = i0; i < i0 + 64; ++i) dpq += wqr[i] * pq[(size_t)i * 512];
    dqu += __shfl_down(dqu, 2); dqu += __shfl_down(dqu, 1);
    dpq += __shfl_down(dpq, 2); dpq += __shfl_down(dpq, 1);
    if (part == 0) np = dpq + 2.f * bq[c] * dqu + (float)R_ * bq[c] * bq[c];
    red[tid] = np;
    __syncthreads();
    for (int s = 128; s > 0; s >>= 1) {
      if (tid < s) red[tid] += red[tid + s];
      __syncthreads();
    }
    if (tid == 0) atomicAdd(&ws[o_nrm], red[0]);
  }
}

// ---------------- 4) kv[b,h] = Wk_h (G_b Wv_h^T) + rank-1 terms ----------------
__global__ __launch_bounds__(256) void kv_k(const float* __restrict__ Wk,
                                            const float* __restrict__ bk,
                                            const float* __restrict__ bv,
                                            float* __restrict__ ws) {
  const int bh = blockIdx.x, b = bh >> 3, h = bh & 7;
  const int o0 = blockIdx.y * 1024 + threadIdx.x * 4;
  const int m = o0 >> 6, d0 = o0 & 63;
  const float* pv = ws + o_Pv + (size_t)b * 131072 + h * 64 + d0;
  const float* wk = Wk + (size_t)(h * 64 + m) * 256;
  float acc[4] = {0.f, 0.f, 0.f, 0.f};
  for (int i = 0; i < 256; ++i) {
    const float w = wk[i];
    const float4 p = *(const float4*)&pv[(size_t)i * 512];
    acc[0] += w * p.x; acc[1] += w * p.y; acc[2] += w * p.z; acc[3] += w * p.w;
  }
  const float wkum = ws[o_wku + b * 512 + h * 64 + m];
  const float bkm = bk[h * 64 + m];
  const float* wvup = ws + o_wvu + b * 512 + h * 64 + d0;
  const float* bvp = bv + h * 64 + d0;
  float rr[4];
#pragma unroll
  for (int e = 0; e < 4; ++e)
    rr[e] = acc[e] + wkum * bvp[e] + bkm * wvup[e] + (float)N_ * bkm * bvp[e];
  *(float4*)&ws[o_kv + (size_t)bh * 4096 + (size_t)m * 64 + d0] =
      make_float4(rr[0], rr[1], rr[2], rr[3]);
}

// ---------------- 5) W1bt/w2bt (bf16, K-major) + C1/C2 (fp32), fold s ----------------
// grid (4 b, 256 i), 512 threads
__global__ __launch_bounds__(512) void w1_k(const float* __restrict__ Wq,
                                            const float* __restrict__ bq,
                                            float* __restrict__ ws) {
  const int b = blockIdx.x, i = blockIdx.y;
  const int c = threadIdx.x, h = c >> 6, d = c & 63;
  const float s = 1.f / (sqrtf(ws[o_nrm]) * sqrtf(ws[o_nrm + 1]));
  const float* kvp = ws + o_kv + (size_t)(b * 8 + h) * 4096 + d;
  unsigned short* W1bt = (unsigned short*)(ws + o_W1bt) + (size_t)b * 131072;
  unsigned short* w2bt = (unsigned short*)(ws + o_w2bt) + b * 4096;
  float a = 0.f;
#pragma unroll 4
  for (int m = 0; m < 64; ++m) a += Wq[(size_t)(h * 64 + m) * 256 + i] * kvp[(size_t)m * 64];
  W1bt[(size_t)c * 256 + i] = f2b(s * a);
  if (c < 16) {
    float w = 0.f;
    if (c < 8) {
      const float* ksp = ws + o_kssum + b * 512 + c * 64;
#pragma unroll 4
      for (int m = 0; m < 64; ++m) w += Wq[(size_t)(c * 64 + m) * 256 + i] * ksp[m];
    }
    w2bt[c * 256 + i] = f2b(s * w);
  }
  if (i == 0) {
    float c1 = 0.f;
    for (int m = 0; m < 64; ++m) c1 += bq[h * 64 + m] * kvp[(size_t)m * 64];
    ws[o_C1 + b * 512 + c] = s * c1 + ws[o_vssum + b * 512 + c];
    if (c < 8) {
      float c2 = 0.f;
      const float* ksp = ws + o_kssum + b * 512 + c * 64;
      for (int m = 0; m < 64; ++m) c2 += bq[c * 64 + m] * ksp[m];
      ws[o_C2 + b * 8 + c] = s * c2 + (float)N_;
    }
  }
}

// ---------------- 6) output: num/den via bf16 MFMA + fused epilogue ----------------
// grid (R/64), 256 threads (4 waves). Wave w owns output cols d = w*16.. for ALL 8 heads.
__global__ __launch_bounds__(256) void out_k(const float* __restrict__ X,
                                             const float* __restrict__ ws,
                                             float* __restrict__ out) {
  const int r0 = blockIdx.x * 64;
  const int b = blockIdx.x >> 8;
  const int tid = threadIdx.x;
  const int lane = tid & 63, wv = tid >> 6;
  const int lc = lane & 15;
  const int klb = (lane >> 4) * 16;

  __shared__ __align__(16) unsigned short Xs[64 * 256];
  __shared__ float invden[64][9];
  char* Xb = (char*)Xs;

  {
    const int row = tid >> 2, kq = (tid & 3) * 64;
    const float* src = X + (size_t)(r0 + row) * DIN + kq;
    const int swz = (row & 7) << 4;
#pragma unroll
    for (int g = 0; g < 8; ++g) {
      const float4 v0 = *(const float4*)(src + g * 8);
      const float4 v1 = *(const float4*)(src + g * 8 + 4);
      short8 p;
      p[0] = (short)f2b(v0.x); p[1] = (short)f2b(v0.y);
      p[2] = (short)f2b(v0.z); p[3] = (short)f2b(v0.w);
      p[4] = (short)f2b(v1.x); p[5] = (short)f2b(v1.y);
      p[6] = (short)f2b(v1.z); p[7] = (short)f2b(v1.w);
      *(short8*)(Xb + ((row * 512 + (kq + g * 8) * 2) ^ swz)) = p;
    }
  }
  __syncthreads();

  const char* W1b = (const char*)((const unsigned short*)(ws + o_W1bt) + (size_t)b * 131072);
  const char* w2b = (const char*)((const unsigned short*)(ws + o_w2bt) + b * 4096);

  f32x4 acc[4][8] = {};
  f32x4 acc2[4] = {};
#pragma unroll
  for (int k32 = 0; k32 < 8; ++k32) {
    const int kbyte = k32 * 64;
    short8 a[4];
#pragma unroll
    for (int fi = 0; fi < 4; ++fi) {
      const int row = fi * 16 + lc;
      a[fi] = *(const short8*)(Xb + ((row * 512 + kbyte + klb) ^ ((row & 7) << 4)));
    }
    short8 bb[8];
#pragma unroll
    for (int fj = 0; fj < 8; ++fj) {
      const int cc = fj * 64 + wv * 16 + lc;
      bb[fj] = *(const short8*)(W1b + cc * 512 + kbyte + klb);
    }
    if (wv == 0) {
      const short8 b2 = *(const short8*)(w2b + lc * 512 + kbyte + klb);
#pragma unroll
      for (int fi = 0; fi < 4; ++fi)
        acc2[fi] = __builtin_amdgcn_mfma_f32_16x16x32_bf16(a[fi], b2, acc2[fi], 0, 0, 0);
    }
#pragma unroll
    for (int fi = 0; fi < 4; ++fi)
#pragma unroll
      for (int fj = 0; fj < 8; ++fj)
        acc[fi][fj] = __builtin_amdgcn_mfma_f32_16x16x32_bf16(a[fi], bb[fj], acc[fi][fj], 0, 0, 0);
  }

  if (wv == 0 && lc < 8) {
    const float c2 = ws[o_C2 + b * 8 + lc];
#pragma unroll
    for (int fi = 0; fi < 4; ++fi) {
      const int rb = fi * 16 + (lane >> 4) * 4;
#pragma unroll
      for (int r = 0; r < 4; ++r) invden[rb + r][lc] = 1.f / (acc2[fi][r] + c2);
    }
  }
  __syncthreads();

  const float* C1p = ws + o_C1 + b * 512;
  float cf[8];
#pragma unroll
  for (int fj = 0; fj < 8; ++fj) cf[fj] = C1p[fj * 64 + wv * 16 + lc];

#pragma unroll
  for (int fi = 0; fi < 4; ++fi) {
    const int rb = fi * 16 + (lane >> 4) * 4;
    float o[4] = {0.f, 0.f, 0.f, 0.f};
#pragma unroll
    for (int fj = 0; fj < 8; ++fj)
#pragma unroll
      for (int r = 0; r < 4; ++r)
        o[r] += (acc[fi][fj][r] + cf[fj]) * invden[rb + r][fj];
#pragma unroll
    for (int r = 0; r < 4; ++r)
      out[(size_t)(r0 + rb + r) * 64 + wv * 16 + lc] = o[r] * 0.125f;
  }
}

extern "C" void kernel_launch(void* const* d_in, const int* in_sizes, int n_in,
                              void* d_out, int out_size, void* d_ws, size_t ws_size,
                              hipStream_t stream) {
  const float* Xq = (const float*)d_in[0];
  const float* Xsrc = (const float*)d_in[1];
  const float* Wq = (const float*)d_in[2];
  const float* bq = (const float*)d_in[3];
  const float* Wk = (const float*)d_in[4];
  const float* bk = (const float*)d_in[5];
  const float* Wv = (const float*)d_in[6];
  const float* bv = (const float*)d_in[7];
  float* out = (float*)d_out;
  float* ws = (float*)d_ws;
  if (ws_size < WS_FLOATS * sizeof(float)) return;  // need ~7.9 MB scratch

  hipMemsetAsync(ws, 0, ZERO_FLOATS * sizeof(float), stream);
  gram_k<<<dim3(32, 8), 512, 0, stream>>>(Xq, Xsrc, ws);
  p_k<<<dim3(8, 4, 9), 256, 0, stream>>>(Wq, Wk, Wv, ws);
  s1_k<<<dim3(8, 5), 256, 0, stream>>>(Wq, Wk, Wv, bq, bk, bv, ws);
  kv_k<<<dim3(32, 4), 256, 0, stream>>>(Wk, bk, bv, ws);
  w1_k<<<dim3(4, 256), 512, 0, stream>>>(Wq, bq, ws);
  out_k<<<dim3(1024), 256, 0, stream>>>(Xq, ws, out);
}

// Round 4
// 244.407 us; speedup vs baseline: 2.1625x; 2.1625x over previous
//
#include <hip/hip_runtime.h>
#include <math.h>

constexpr int B_ = 4;
constexpr int N_ = 16384;
constexpr int DIN = 256;
constexpr int DOUT = 512;
constexpr int R_ = B_ * N_;   // 65536

typedef __attribute__((ext_vector_type(4))) float f32x4;
typedef __attribute__((ext_vector_type(8))) short short8;

// ---------------- workspace layout (float offsets) ----------------
constexpr size_t o_Gq    = 0;         // 256x256 query gram, part 0 (z=4,5)
constexpr size_t o_Gq2   = 65536;     // 256x256 query gram, part 1 (z=6,7)
constexpr size_t o_Gs    = 131072;    // 4 x 256x256 per-batch source grams
constexpr size_t o_uq    = 393216;    // 256 colsum(query)
constexpr size_t o_us    = 393472;    // 4x256 colsum(source_b)
constexpr size_t o_nrm   = 394496;    // [0]=nq2 [1]=nk2
constexpr size_t ZERO_FLOATS = 394498; // atomically accumulated region -> zero each call
constexpr size_t o_Pv    = 394560;    // 4 x (256x512): G_b @ Wv^T
constexpr size_t o_Pk    = 918848;    // 4 x (256x512): G_b @ Wk^T
constexpr size_t o_Pq    = 1443136;   // 256x512: Gq @ Wq^T
constexpr size_t o_wku   = 1574208;   // 4x512
constexpr size_t o_wvu   = 1576256;   // 4x512
constexpr size_t o_kssum = 1578304;   // 4x512
constexpr size_t o_vssum = 1580352;   // 4x512
constexpr size_t o_kv    = 1582400;   // 4x8x64x64 raw K^T V
constexpr size_t o_W1bt  = 1713472;   // bf16: 4 x [512 c][256 k]  (s folded in)
constexpr size_t o_w2bt  = 1975616;   // bf16: 4 x [16 c][256 k]   (rows 8..15 zero)
constexpr size_t o_C1    = 1983808;   // 4x512 fp32
constexpr size_t o_C2    = 1985856;   // 4x8 fp32
constexpr size_t WS_FLOATS = 1985888; // ~7.9 MB

static __device__ __forceinline__ float dot4(float4 a, float4 b) {
  return a.x * b.x + a.y * b.y + a.z * b.z + a.w * b.w;
}

// fp32 -> bf16 bits, round-to-nearest-even
static __device__ __forceinline__ unsigned short f2b(float f) {
  unsigned int u = __float_as_uint(f);
  u = (u + 0x7FFFu + ((u >> 16) & 1u)) >> 16;
  return (unsigned short)u;
}

// LDS swizzle for the gram transpose tile: mixes col low bits AND col high bits
// (write lanes vary only c>>4; read lanes vary c&7 -> both spread across banks)
#define SWZB(c) ((((c) ^ ((c) >> 4)) & 7) << 4)

// ---------------- gram_k pipeline stages (macros => all indices compile-time,
// no lambdas, no runtime indexing into register arrays: see rule #20) --------
#define GK_ISSUE(KB)                                                          \
  _Pragma("unroll") for (int rw = 0; rw < 2; ++rw)                            \
  _Pragma("unroll") for (int g = 0; g < 4; ++g)                               \
      vreg[rw * 4 + g] =                                                      \
          *(const float4*)(Ab0 + (size_t)((KB) * 64 + 2 * p + rw) * DIN + g * 4);

#define GK_COMMIT(BUF)                                                        \
  {                                                                           \
    char* dst = Lb + (BUF) * 32768;                                           \
    _Pragma("unroll") for (int g = 0; g < 4; ++g) {                           \
      const float a0v[4] = {vreg[g].x, vreg[g].y, vreg[g].z, vreg[g].w};      \
      const float a1v[4] = {vreg[4 + g].x, vreg[4 + g].y, vreg[4 + g].z,      \
                            vreg[4 + g].w};                                   \
      _Pragma("unroll") for (int j = 0; j < 4; ++j) {                         \
        const int c = colg + g * 4 + j;                                       \
        us16[g * 4 + j] += a0v[j] + a1v[j];                                   \
        const unsigned int pk = (unsigned int)f2b(a0v[j]) |                   \
                                ((unsigned int)f2b(a1v[j]) << 16);            \
        *(unsigned int*)(dst + ((c * 128 + p * 4) ^ SWZB(c))) = pk;           \
      }                                                                       \
    }                                                                         \
  }

#define GK_COMPUTE(BUF)                                                       \
  {                                                                           \
    const char* srcb = Lb + (BUF) * 32768;                                    \
    _Pragma("unroll") for (int ks = 0; ks < 2; ++ks) {                        \
      const int kb2 = ks * 64 + klb;                                          \
      short8 afr[4];                                                          \
      _Pragma("unroll") for (int fi = 0; fi < 4; ++fi) {                      \
        const int cc = i0w + fi * 16 + lc;                                    \
        afr[fi] = *(const short8*)(srcb + ((cc * 128 + kb2) ^ SWZB(cc)));     \
      }                                                                       \
      _Pragma("unroll") for (int fj = 0; fj < 8; ++fj) {                      \
        const int cc = j0w + fj * 16 + lc;                                    \
        const short8 bfr =                                                    \
            *(const short8*)(srcb + ((cc * 128 + kb2) ^ SWZB(cc)));           \
        _Pragma("unroll") for (int fi = 0; fi < 4; ++fi)                      \
            acc[fi][fj] = __builtin_amdgcn_mfma_f32_16x16x32_bf16(            \
                afr[fi], bfr, acc[fi][fj], 0, 0, 0);                          \
      }                                                                       \
    }                                                                         \
  }

// ---------------- 1) Grams: G = A^T A (256x256) + colsum, bf16 MFMA ----------------
// grid (32 chunks of 512 rows, 8 z): z<4 -> source batch z ; z>=4 -> query quarter
__global__ __launch_bounds__(512) void gram_k(const float* __restrict__ Xq,
                                              const float* __restrict__ Xsrc,
                                              float* __restrict__ ws) {
  const int z = blockIdx.y;
  const float* A;
  float* G;
  float* u;
  if (z < 4) {
    A = Xsrc + (size_t)z * N_ * DIN;
    G = ws + o_Gs + (size_t)z * 65536;
    u = ws + o_us + z * 256;
  } else {
    A = Xq + (size_t)(z - 4) * N_ * DIN;
    G = ws + ((z & 2) ? o_Gq2 : o_Gq);
    u = ws + o_uq;
  }
  const int row0 = blockIdx.x * 512;
  const int tid = threadIdx.x;
  const int lane = tid & 63, wv = tid >> 6;
  const int i0w = (wv >> 1) * 64;       // wave tile: 64 (i) x 128 (j)
  const int j0w = (wv & 1) * 128;
  const int lc = lane & 15;
  const int klb = (lane >> 4) * 16;

  // double-buffered transposed tile: [buf][col][64 rows] bf16, swizzled. 2x32KB.
  __shared__ __align__(16) unsigned short Xt[2 * 256 * 64];
  char* Lb = (char*)Xt;

  const int p = tid >> 4;             // 0..31: row pair within 64-row chunk
  const int colg = (tid & 15) * 16;   // this thread's 16 columns
  const float* Ab0 = A + (size_t)row0 * DIN + colg;

  float us16[16] = {};
  f32x4 acc[4][8] = {};
  float4 vreg[8];

  // straight-line double-buffered pipeline over 8 chunks of 64 rows
  GK_ISSUE(0) GK_COMMIT(0) __syncthreads();
  GK_ISSUE(1) GK_COMPUTE(0) GK_COMMIT(1) __syncthreads();
  GK_ISSUE(2) GK_COMPUTE(1) GK_COMMIT(0) __syncthreads();
  GK_ISSUE(3) GK_COMPUTE(0) GK_COMMIT(1) __syncthreads();
  GK_ISSUE(4) GK_COMPUTE(1) GK_COMMIT(0) __syncthreads();
  GK_ISSUE(5) GK_COMPUTE(0) GK_COMMIT(1) __syncthreads();
  GK_ISSUE(6) GK_COMPUTE(1) GK_COMMIT(0) __syncthreads();
  GK_ISSUE(7) GK_COMPUTE(0) GK_COMMIT(1) __syncthreads();
  GK_COMPUTE(1)

  // G atomics — STATIC index order (runtime-rotated indexing spilled acc: rule #20)
#pragma unroll
  for (int fi = 0; fi < 4; ++fi) {
    const int ib = i0w + fi * 16 + (lane >> 4) * 4;
#pragma unroll
    for (int fj = 0; fj < 8; ++fj) {
      const int jb = j0w + fj * 16 + lc;
#pragma unroll
      for (int r = 0; r < 4; ++r)
        atomicAdd(&G[(size_t)(ib + r) * DIN + jb], acc[fi][fj][r]);
    }
  }

  // colsum reduce (fp32-exact, accumulated from pre-conversion values)
  __syncthreads();
  float* red = (float*)Xt;
#pragma unroll
  for (int j = 0; j < 4; ++j)
    *(float4*)&red[p * 256 + colg + j * 4] =
        make_float4(us16[j * 4], us16[j * 4 + 1], us16[j * 4 + 2], us16[j * 4 + 3]);
  __syncthreads();
  if (tid < 256) {
    float s = 0.f;
#pragma unroll 8
    for (int pp = 0; pp < 32; ++pp) s += red[pp * 256 + tid];
    atomicAdd(&u[tid], s);
  }
}

// ---------------- 2) P = G @ W^T  (256x512, K=256) ----------------
// grid (8 ctiles, 4 itiles, 9 jobs); job 8 sums Gq + Gq2 on the fly
__global__ __launch_bounds__(256) void p_k(const float* __restrict__ Wq,
                                           const float* __restrict__ Wk,
                                           const float* __restrict__ Wv,
                                           float* __restrict__ ws) {
  const int job = blockIdx.z;
  const float* G;
  const float* G2 = nullptr;
  const float* W;
  float* P;
  if (job < 4) {
    G = ws + o_Gs + (size_t)job * 65536; W = Wv; P = ws + o_Pv + (size_t)job * 131072;
  } else if (job < 8) {
    G = ws + o_Gs + (size_t)(job - 4) * 65536; W = Wk; P = ws + o_Pk + (size_t)(job - 4) * 131072;
  } else {
    G = ws + o_Gq; G2 = ws + o_Gq2; W = Wq; P = ws + o_Pq;
  }
  const int c0 = blockIdx.x * 64, i0 = blockIdx.y * 64;
  __shared__ float Gt[64][68];
  __shared__ float Wt[64][68];
  const int tid = threadIdx.x;
  const int ty = tid >> 4, tx = tid & 15;
  float acc[4][4] = {};
  for (int k0 = 0; k0 < 256; k0 += 64) {
    __syncthreads();
#pragma unroll
    for (int pg = 0; pg < 4; ++pg) {
      const int idx = tid + pg * 256;
      const int row = idx >> 4, jq = (idx & 15) * 4;
      float4 g = *(const float4*)&G[(size_t)(i0 + row) * DIN + k0 + jq];
      if (G2) {
        const float4 h = *(const float4*)&G2[(size_t)(i0 + row) * DIN + k0 + jq];
        g.x += h.x; g.y += h.y; g.z += h.z; g.w += h.w;
      }
      Gt[jq + 0][row] = g.x; Gt[jq + 1][row] = g.y; Gt[jq + 2][row] = g.z; Gt[jq + 3][row] = g.w;
      const float4 w = *(const float4*)&W[(size_t)(c0 + row) * DIN + k0 + jq];
      Wt[jq + 0][row] = w.x; Wt[jq + 1][row] = w.y; Wt[jq + 2][row] = w.z; Wt[jq + 3][row] = w.w;
    }
    __syncthreads();
#pragma unroll
    for (int k = 0; k < 64; ++k) {
      const float4 a = *(const float4*)&Gt[k][ty * 4];
      const float4 bb = *(const float4*)&Wt[k][tx * 4];
      const float av[4] = {a.x, a.y, a.z, a.w};
      const float bv_[4] = {bb.x, bb.y, bb.z, bb.w};
#pragma unroll
      for (int ii = 0; ii < 4; ++ii)
#pragma unroll
        for (int jj = 0; jj < 4; ++jj) acc[ii][jj] += av[ii] * bv_[jj];
    }
  }
#pragma unroll
  for (int ii = 0; ii < 4; ++ii)
    *(float4*)&P[(size_t)(i0 + ty * 4 + ii) * DOUT + c0 + tx * 4] =
        make_float4(acc[ii][0], acc[ii][1], acc[ii][2], acc[ii][3]);
}

// ---------------- 3) small bilinears: wku/wvu, ks_sum/vs_sum, nq2/nk2 ----------------
__global__ __launch_bounds__(256) void s1_k(const float* __restrict__ Wq,
                                            const float* __restrict__ Wk,
                                            const float* __restrict__ Wv,
                                            const float* __restrict__ bq,
                                            const float* __restrict__ bk,
                                            const float* __restrict__ bv,
                                            float* __restrict__ ws) {
  const int tid = threadIdx.x;
  const int c = blockIdx.x * 64 + (tid >> 2);
  const int part = tid & 3;
  const int i0 = part * 64;
  const int job = blockIdx.y;
  __shared__ float red[256];
  float np = 0.f;
  if (job < 4) {
    const int b = job;
    const float* ub = ws + o_us + b * 256;
    const float* wkr = Wk + (size_t)c * 256;
    const float* wvr = Wv + (size_t)c * 256;
    const float* pk = ws + o_Pk + (size_t)b * 131072 + c;
    float dku = 0.f, dvu = 0.f, dpk = 0.f;
#pragma unroll 4
    for (int t = 0; t < 16; ++t) {
      const float4 u4 = *(const float4*)&ub[i0 + t * 4];
      dku += dot4(*(const float4*)&wkr[i0 + t * 4], u4);
      dvu += dot4(*(const float4*)&wvr[i0 + t * 4], u4);
    }
    for (int i = i0; i < i0 + 64; ++i) dpk += wkr[i] * pk[(size_t)i * 512];
    dku += __shfl_down(dku, 2); dku += __shfl_down(dku, 1);
    dvu += __shfl_down(dvu, 2); dvu += __shfl_down(dvu, 1);
    dpk += __shfl_down(dpk, 2); dpk += __shfl_down(dpk, 1);
    if (part == 0) {
      ws[o_wku + b * 512 + c] = dku;
      ws[o_wvu + b * 512 + c] = dvu;
      ws[o_kssum + b * 512 + c] = dku + (float)N_ * bk[c];
      ws[o_vssum + b * 512 + c] = dvu + (float)N_ * bv[c];
      np = dpk + 2.f * bk[c] * dku + (float)N_ * bk[c] * bk[c];
    }
    red[tid] = np;
    __syncthreads();
    for (int s = 128; s > 0; s >>= 1) {
      if (tid < s) red[tid] += red[tid + s];
      __syncthreads();
    }
    if (tid == 0) atomicAdd(&ws[o_nrm + 1], red[0]);
  } else {
    const float* uq = ws + o_uq;
    const float* wqr = Wq + (size_t)c * 256;
    const float* pq = ws + o_Pq + c;
    float dqu = 0.f, dpq = 0.f;
#pragma unroll 4
    for (int t = 0; t < 16; ++t)
      dqu += dot4(*(const float4*)&wqr[i0 + t * 4], *(const float4*)&uq[i0 + t * 4]);
    for (int i = i0; i < i0 + 64; ++i) dpq += wqr[i] * pq[(size_t)i * 512];
    dqu += __shfl_down(dqu, 2); dqu += __shfl_down(dqu, 1);
    dpq += __shfl_down(dpq, 2); dpq += __shfl_down(dpq, 1);
    if (part == 0) np = dpq + 2.f * bq[c] * dqu + (float)R_ * bq[c] * bq[c];
    red[tid] = np;
    __syncthreads();
    for (int s = 128; s > 0; s >>= 1) {
      if (tid < s) red[tid] += red[tid + s];
      __syncthreads();
    }
    if (tid == 0) atomicAdd(&ws[o_nrm], red[0]);
  }
}

// ---------------- 4) kv[b,h] = Wk_h (G_b Wv_h^T) + rank-1 terms ----------------
__global__ __launch_bounds__(256) void kv_k(const float* __restrict__ Wk,
                                            const float* __restrict__ bk,
                                            const float* __restrict__ bv,
                                            float* __restrict__ ws) {
  const int bh = blockIdx.x, b = bh >> 3, h = bh & 7;
  const int o0 = blockIdx.y * 1024 + threadIdx.x * 4;
  const int m = o0 >> 6, d0 = o0 & 63;
  const float* pv = ws + o_Pv + (size_t)b * 131072 + h * 64 + d0;
  const float* wk = Wk + (size_t)(h * 64 + m) * 256;
  float acc[4] = {0.f, 0.f, 0.f, 0.f};
  for (int i = 0; i < 256; ++i) {
    const float w = wk[i];
    const float4 p = *(const float4*)&pv[(size_t)i * 512];
    acc[0] += w * p.x; acc[1] += w * p.y; acc[2] += w * p.z; acc[3] += w * p.w;
  }
  const float wkum = ws[o_wku + b * 512 + h * 64 + m];
  const float bkm = bk[h * 64 + m];
  const float* wvup = ws + o_wvu + b * 512 + h * 64 + d0;
  const float* bvp = bv + h * 64 + d0;
  float rr[4];
#pragma unroll
  for (int e = 0; e < 4; ++e)
    rr[e] = acc[e] + wkum * bvp[e] + bkm * wvup[e] + (float)N_ * bkm * bvp[e];
  *(float4*)&ws[o_kv + (size_t)bh * 4096 + (size_t)m * 64 + d0] =
      make_float4(rr[0], rr[1], rr[2], rr[3]);
}

// ---------------- 5) W1bt/w2bt (bf16, K-major) + C1/C2 (fp32), fold s ----------------
// grid (4 b, 256 i), 512 threads
__global__ __launch_bounds__(512) void w1_k(const float* __restrict__ Wq,
                                            const float* __restrict__ bq,
                                            float* __restrict__ ws) {
  const int b = blockIdx.x, i = blockIdx.y;
  const int c = threadIdx.x, h = c >> 6, d = c & 63;
  const float s = 1.f / (sqrtf(ws[o_nrm]) * sqrtf(ws[o_nrm + 1]));
  const float* kvp = ws + o_kv + (size_t)(b * 8 + h) * 4096 + d;
  unsigned short* W1bt = (unsigned short*)(ws + o_W1bt) + (size_t)b * 131072;
  unsigned short* w2bt = (unsigned short*)(ws + o_w2bt) + b * 4096;
  float a = 0.f;
#pragma unroll 4
  for (int m = 0; m < 64; ++m) a += Wq[(size_t)(h * 64 + m) * 256 + i] * kvp[(size_t)m * 64];
  W1bt[(size_t)c * 256 + i] = f2b(s * a);
  if (c < 16) {
    float w = 0.f;
    if (c < 8) {
      const float* ksp = ws + o_kssum + b * 512 + c * 64;
#pragma unroll 4
      for (int m = 0; m < 64; ++m) w += Wq[(size_t)(c * 64 + m) * 256 + i] * ksp[m];
    }
    w2bt[c * 256 + i] = f2b(s * w);
  }
  if (i == 0) {
    float c1 = 0.f;
    for (int m = 0; m < 64; ++m) c1 += bq[h * 64 + m] * kvp[(size_t)m * 64];
    ws[o_C1 + b * 512 + c] = s * c1 + ws[o_vssum + b * 512 + c];
    if (c < 8) {
      float c2 = 0.f;
      const float* ksp = ws + o_kssum + b * 512 + c * 64;
      for (int m = 0; m < 64; ++m) c2 += bq[c * 64 + m] * ksp[m];
      ws[o_C2 + b * 8 + c] = s * c2 + (float)N_;
    }
  }
}

// ---------------- 6) output: num/den via bf16 MFMA + fused epilogue ----------------
// grid (R/64), 256 threads (4 waves). Wave w owns output cols d = w*16.. for ALL 8 heads.
__global__ __launch_bounds__(256) void out_k(const float* __restrict__ X,
                                             const float* __restrict__ ws,
                                             float* __restrict__ out) {
  const int r0 = blockIdx.x * 64;
  const int b = blockIdx.x >> 8;
  const int tid = threadIdx.x;
  const int lane = tid & 63, wv = tid >> 6;
  const int lc = lane & 15;
  const int klb = (lane >> 4) * 16;

  __shared__ __align__(16) unsigned short Xs[64 * 256];
  __shared__ float invden[64][9];
  char* Xb = (char*)Xs;

  {
    const int row = tid >> 2, kq = (tid & 3) * 64;
    const float* src = X + (size_t)(r0 + row) * DIN + kq;
    const int swz = (row & 7) << 4;
#pragma unroll
    for (int g = 0; g < 8; ++g) {
      const float4 v0 = *(const float4*)(src + g * 8);
      const float4 v1 = *(const float4*)(src + g * 8 + 4);
      short8 p;
      p[0] = (short)f2b(v0.x); p[1] = (short)f2b(v0.y);
      p[2] = (short)f2b(v0.z); p[3] = (short)f2b(v0.w);
      p[4] = (short)f2b(v1.x); p[5] = (short)f2b(v1.y);
      p[6] = (short)f2b(v1.z); p[7] = (short)f2b(v1.w);
      *(short8*)(Xb + ((row * 512 + (kq + g * 8) * 2) ^ swz)) = p;
    }
  }
  __syncthreads();

  const char* W1b = (const char*)((const unsigned short*)(ws + o_W1bt) + (size_t)b * 131072);
  const char* w2b = (const char*)((const unsigned short*)(ws + o_w2bt) + b * 4096);

  f32x4 acc[4][8] = {};
  f32x4 acc2[4] = {};
#pragma unroll
  for (int k32 = 0; k32 < 8; ++k32) {
    const int kbyte = k32 * 64;
    short8 a[4];
#pragma unroll
    for (int fi = 0; fi < 4; ++fi) {
      const int row = fi * 16 + lc;
      a[fi] = *(const short8*)(Xb + ((row * 512 + kbyte + klb) ^ ((row & 7) << 4)));
    }
    short8 bb[8];
#pragma unroll
    for (int fj = 0; fj < 8; ++fj) {
      const int cc = fj * 64 + wv * 16 + lc;
      bb[fj] = *(const short8*)(W1b + cc * 512 + kbyte + klb);
    }
    if (wv == 0) {
      const short8 b2 = *(const short8*)(w2b + lc * 512 + kbyte + klb);
#pragma unroll
      for (int fi = 0; fi < 4; ++fi)
        acc2[fi] = __builtin_amdgcn_mfma_f32_16x16x32_bf16(a[fi], b2, acc2[fi], 0, 0, 0);
    }
#pragma unroll
    for (int fi = 0; fi < 4; ++fi)
#pragma unroll
      for (int fj = 0; fj < 8; ++fj)
        acc[fi][fj] = __builtin_amdgcn_mfma_f32_16x16x32_bf16(a[fi], bb[fj], acc[fi][fj], 0, 0, 0);
  }

  if (wv == 0 && lc < 8) {
    const float c2 = ws[o_C2 + b * 8 + lc];
#pragma unroll
    for (int fi = 0; fi < 4; ++fi) {
      const int rb = fi * 16 + (lane >> 4) * 4;
#pragma unroll
      for (int r = 0; r < 4; ++r) invden[rb + r][lc] = 1.f / (acc2[fi][r] + c2);
    }
  }
  __syncthreads();

  const float* C1p = ws + o_C1 + b * 512;
  float cf[8];
#pragma unroll
  for (int fj = 0; fj < 8; ++fj) cf[fj] = C1p[fj * 64 + wv * 16 + lc];

#pragma unroll
  for (int fi = 0; fi < 4; ++fi) {
    const int rb = fi * 16 + (lane >> 4) * 4;
    float o[4] = {0.f, 0.f, 0.f, 0.f};
#pragma unroll
    for (int fj = 0; fj < 8; ++fj)
#pragma unroll
      for (int r = 0; r < 4; ++r)
        o[r] += (acc[fi][fj][r] + cf[fj]) * invden[rb + r][fj];
#pragma unroll
    for (int r = 0; r < 4; ++r)
      out[(size_t)(r0 + rb + r) * 64 + wv * 16 + lc] = o[r] * 0.125f;
  }
}

extern "C" void kernel_launch(void* const* d_in, const int* in_sizes, int n_in,
                              void* d_out, int out_size, void* d_ws, size_t ws_size,
                              hipStream_t stream) {
  const float* Xq = (const float*)d_in[0];
  const float* Xsrc = (const float*)d_in[1];
  const float* Wq = (const float*)d_in[2];
  const float* bq = (const float*)d_in[3];
  const float* Wk = (const float*)d_in[4];
  const float* bk = (const float*)d_in[5];
  const float* Wv = (const float*)d_in[6];
  const float* bv = (const float*)d_in[7];
  float* out = (float*)d_out;
  float* ws = (float*)d_ws;
  if (ws_size < WS_FLOATS * sizeof(float)) return;  // need ~7.9 MB scratch

  hipMemsetAsync(ws, 0, ZERO_FLOATS * sizeof(float), stream);
  gram_k<<<dim3(32, 8), 512, 0, stream>>>(Xq, Xsrc, ws);
  p_k<<<dim3(8, 4, 9), 256, 0, stream>>>(Wq, Wk, Wv, ws);
  s1_k<<<dim3(8, 5), 256, 0, stream>>>(Wq, Wk, Wv, bq, bk, bv, ws);
  kv_k<<<dim3(32, 4), 256, 0, stream>>>(Wk, bk, bv, ws);
  w1_k<<<dim3(4, 256), 512, 0, stream>>>(Wq, bq, ws);
  out_k<<<dim3(1024), 256, 0, stream>>>(Xq, ws, out);
}

// Round 5
// 189.364 us; speedup vs baseline: 2.7911x; 1.2907x over previous
//
#include <hip/hip_runtime.h>
#include <math.h>

constexpr int B_ = 4;
constexpr int N_ = 16384;
constexpr int DIN = 256;
constexpr int DOUT = 512;
constexpr int R_ = B_ * N_;   // 65536

typedef __attribute__((ext_vector_type(4))) float f32x4;
typedef __attribute__((ext_vector_type(8))) short short8;

// ---------------- workspace layout (float offsets) ----------------
constexpr size_t o_Gq    = 0;         // 256x256 query gram, part 0 (z=4,5)
constexpr size_t o_Gq2   = 65536;     // 256x256 query gram, part 1 (z=6,7)
constexpr size_t o_Gs    = 131072;    // 4 x 256x256 per-batch source grams
constexpr size_t o_uq    = 393216;    // 256 colsum(query)
constexpr size_t o_us    = 393472;    // 4x256 colsum(source_b)
constexpr size_t o_nrm   = 394496;    // [0]=nq2 [1]=nk2
constexpr size_t ZERO_FLOATS = 394498; // atomically accumulated region -> zero each call
constexpr size_t o_Pv    = 394560;    // 4 x (256x512): G_b @ Wv^T
constexpr size_t o_Pk    = 918848;    // 4 x (256x512): G_b @ Wk^T
constexpr size_t o_Pq    = 1443136;   // 256x512: Gq @ Wq^T
constexpr size_t o_wku   = 1574208;   // 4x512
constexpr size_t o_wvu   = 1576256;   // 4x512
constexpr size_t o_kssum = 1578304;   // 4x512
constexpr size_t o_vssum = 1580352;   // 4x512
constexpr size_t o_kv    = 1582400;   // 4x8x64x64 raw K^T V
constexpr size_t o_W1bt  = 1713472;   // bf16: 4 x [512 c][256 k]  (s folded in)
constexpr size_t o_w2bt  = 1975616;   // bf16: 4 x [16 c][256 k]   (rows 8..15 zero)
constexpr size_t o_C1    = 1983808;   // 4x512 fp32
constexpr size_t o_C2    = 1985856;   // 4x8 fp32
constexpr size_t WS_FLOATS = 1985888; // ~7.9 MB (minimum)
// optional fast path: per-block gram partials (256 x 256x256 fp32 = 64 MB)
constexpr size_t o_part  = WS_FLOATS;
constexpr size_t BIG_FLOATS = o_part + (size_t)256 * 65536; // ~75 MB

static __device__ __forceinline__ float dot4(float4 a, float4 b) {
  return a.x * b.x + a.y * b.y + a.z * b.z + a.w * b.w;
}

// fp32 -> bf16 bits, round-to-nearest-even
static __device__ __forceinline__ unsigned short f2b(float f) {
  unsigned int u = __float_as_uint(f);
  u = (u + 0x7FFFu + ((u >> 16) & 1u)) >> 16;
  return (unsigned short)u;
}

// ---------------- 1) Grams: G = A^T A (256x256) + colsum, bf16 MFMA ----------------
// grid (32 chunks of 512 rows, 8 z): z<4 -> source batch z ; z>=4 -> query quarter.
// Epilogue: per-block partial STORES (if part != nullptr) -> gred_k reduce; else
// fp32 atomics (fallback; measured atomic-throughput-bound at ~100us in R2).
__global__ __launch_bounds__(512) void gram_k(const float* __restrict__ Xq,
                                              const float* __restrict__ Xsrc,
                                              float* __restrict__ ws,
                                              float* __restrict__ part) {
  const int z = blockIdx.y;
  const float* A;
  float* G;
  float* u;
  if (z < 4) {
    A = Xsrc + (size_t)z * N_ * DIN;
    G = ws + o_Gs + (size_t)z * 65536;
    u = ws + o_us + z * 256;
  } else {
    A = Xq + (size_t)(z - 4) * N_ * DIN;
    G = ws + ((z & 2) ? o_Gq2 : o_Gq);
    u = ws + o_uq;
  }
  const int row0 = blockIdx.x * 512;
  const int tid = threadIdx.x;
  const int lane = tid & 63, wv = tid >> 6;
  const int i0w = (wv >> 1) * 64;       // wave tile: 64 (i) x 128 (j)
  const int j0w = (wv & 1) * 128;
  const int lc = lane & 15;
  const int klb = (lane >> 4) * 16;     // byte offset of this lane's k-octet

  // LDS: A-chunk transposed [256 cols][64 rows] bf16, XOR-swizzled (128B rows)
  __shared__ __align__(16) unsigned short As[256 * 64];
  char* Ab = (char*)As;

  const int c = tid & 255;              // staging: this thread's column
  const int half = tid >> 8;            // rows half*32 .. +32
  float usum = 0.f;

  f32x4 acc[4][8] = {};

  for (int kb = 0; kb < 512; kb += 64) {
    __syncthreads();
    // stage rows [row0+kb, +64): thread reads 32 fp32 down column c, packs bf16
    {
      const float* src = A + (size_t)(row0 + kb + half * 32) * DIN + c;
      const int swz = (c & 7) << 4;
#pragma unroll
      for (int g = 0; g < 4; ++g) {
        float v[8];
#pragma unroll
        for (int e = 0; e < 8; ++e) v[e] = src[(size_t)(g * 8 + e) * DIN];
#pragma unroll
        for (int e = 0; e < 8; ++e) usum += v[e];
        short8 p;
#pragma unroll
        for (int e = 0; e < 8; ++e) p[e] = (short)f2b(v[e]);
        *(short8*)(Ab + ((c * 128 + (half * 32 + g * 8) * 2) ^ swz)) = p;
      }
    }
    __syncthreads();
#pragma unroll
    for (int ks = 0; ks < 2; ++ks) {
      const int kbyte = ks * 64;
      short8 a[4], b[8];
#pragma unroll
      for (int fi = 0; fi < 4; ++fi) {
        const int cc = i0w + fi * 16 + lc;
        a[fi] = *(const short8*)(Ab + ((cc * 128 + kbyte + klb) ^ ((cc & 7) << 4)));
      }
#pragma unroll
      for (int fj = 0; fj < 8; ++fj) {
        const int cc = j0w + fj * 16 + lc;
        b[fj] = *(const short8*)(Ab + ((cc * 128 + kbyte + klb) ^ ((cc & 7) << 4)));
      }
#pragma unroll
      for (int fi = 0; fi < 4; ++fi)
#pragma unroll
        for (int fj = 0; fj < 8; ++fj)
          acc[fi][fj] = __builtin_amdgcn_mfma_f32_16x16x32_bf16(a[fi], b[fj], acc[fi][fj], 0, 0, 0);
    }
  }

  if (part) {
    // fast path: plain stores of this block's partial tile (full write BW)
    float* P = part + (size_t)(z * 32 + blockIdx.x) * 65536;
#pragma unroll
    for (int fi = 0; fi < 4; ++fi) {
      const int ib = i0w + fi * 16 + (lane >> 4) * 4;
#pragma unroll
      for (int fj = 0; fj < 8; ++fj) {
        const int jb = j0w + fj * 16 + lc;
#pragma unroll
        for (int r = 0; r < 4; ++r)
          P[(size_t)(ib + r) * DIN + jb] = acc[fi][fj][r];
      }
    }
  } else {
    // fallback: device atomics (atomic-throughput-bound)
#pragma unroll
    for (int fi = 0; fi < 4; ++fi) {
      const int ib = i0w + fi * 16 + (lane >> 4) * 4;
#pragma unroll
      for (int fj = 0; fj < 8; ++fj) {
        const int jb = j0w + fj * 16 + lc;
#pragma unroll
        for (int r = 0; r < 4; ++r)
          atomicAdd(&G[(size_t)(ib + r) * DIN + jb], acc[fi][fj][r]);
      }
    }
  }

  // colsum reduce (fp32-exact, accumulated from pre-conversion values)
  __syncthreads();
  float* red = (float*)As;
  red[tid] = usum;
  __syncthreads();
  if (tid < 256) atomicAdd(&u[tid], red[tid] + red[tid + 256]);
}

// ---------------- 1b) reduce gram partials -> G buffers ----------------
// grid (64, 6): j<4 -> Gs[j] (sum 32); j=4 -> Gq (sum 64, z=4,5); j=5 -> Gq2 (z=6,7)
__global__ __launch_bounds__(256) void gred_k(const float* __restrict__ part,
                                              float* __restrict__ ws) {
  const int j = blockIdx.y;
  const size_t o = (size_t)blockIdx.x * 1024 + (size_t)threadIdx.x * 4;
  const float* src;
  float* dst;
  int np;
  if (j < 4) {
    src = part + (size_t)j * 32 * 65536; dst = ws + o_Gs + (size_t)j * 65536; np = 32;
  } else if (j == 4) {
    src = part + (size_t)128 * 65536; dst = ws + o_Gq; np = 64;
  } else {
    src = part + (size_t)192 * 65536; dst = ws + o_Gq2; np = 64;
  }
  float sx = 0.f, sy = 0.f, sz = 0.f, sw = 0.f;
  for (int i = 0; i < np; ++i) {
    const float4 v = *(const float4*)&src[(size_t)i * 65536 + o];
    sx += v.x; sy += v.y; sz += v.z; sw += v.w;
  }
  *(float4*)&dst[o] = make_float4(sx, sy, sz, sw);
}

// ---------------- 2) P = G @ W^T  (256x512, K=256) ----------------
// grid (8 ctiles, 4 itiles, 9 jobs); job 8 sums Gq + Gq2 on the fly
__global__ __launch_bounds__(256) void p_k(const float* __restrict__ Wq,
                                           const float* __restrict__ Wk,
                                           const float* __restrict__ Wv,
                                           float* __restrict__ ws) {
  const int job = blockIdx.z;
  const float* G;
  const float* G2 = nullptr;
  const float* W;
  float* P;
  if (job < 4) {
    G = ws + o_Gs + (size_t)job * 65536; W = Wv; P = ws + o_Pv + (size_t)job * 131072;
  } else if (job < 8) {
    G = ws + o_Gs + (size_t)(job - 4) * 65536; W = Wk; P = ws + o_Pk + (size_t)(job - 4) * 131072;
  } else {
    G = ws + o_Gq; G2 = ws + o_Gq2; W = Wq; P = ws + o_Pq;
  }
  const int c0 = blockIdx.x * 64, i0 = blockIdx.y * 64;
  __shared__ float Gt[64][68];
  __shared__ float Wt[64][68];
  const int tid = threadIdx.x;
  const int ty = tid >> 4, tx = tid & 15;
  float acc[4][4] = {};
  for (int k0 = 0; k0 < 256; k0 += 64) {
    __syncthreads();
#pragma unroll
    for (int pg = 0; pg < 4; ++pg) {
      const int idx = tid + pg * 256;
      const int row = idx >> 4, jq = (idx & 15) * 4;
      float4 g = *(const float4*)&G[(size_t)(i0 + row) * DIN + k0 + jq];
      if (G2) {
        const float4 h = *(const float4*)&G2[(size_t)(i0 + row) * DIN + k0 + jq];
        g.x += h.x; g.y += h.y; g.z += h.z; g.w += h.w;
      }
      Gt[jq + 0][row] = g.x; Gt[jq + 1][row] = g.y; Gt[jq + 2][row] = g.z; Gt[jq + 3][row] = g.w;
      const float4 w = *(const float4*)&W[(size_t)(c0 + row) * DIN + k0 + jq];
      Wt[jq + 0][row] = w.x; Wt[jq + 1][row] = w.y; Wt[jq + 2][row] = w.z; Wt[jq + 3][row] = w.w;
    }
    __syncthreads();
#pragma unroll
    for (int k = 0; k < 64; ++k) {
      const float4 a = *(const float4*)&Gt[k][ty * 4];
      const float4 bb = *(const float4*)&Wt[k][tx * 4];
      const float av[4] = {a.x, a.y, a.z, a.w};
      const float bv_[4] = {bb.x, bb.y, bb.z, bb.w};
#pragma unroll
      for (int ii = 0; ii < 4; ++ii)
#pragma unroll
        for (int jj = 0; jj < 4; ++jj) acc[ii][jj] += av[ii] * bv_[jj];
    }
  }
#pragma unroll
  for (int ii = 0; ii < 4; ++ii)
    *(float4*)&P[(size_t)(i0 + ty * 4 + ii) * DOUT + c0 + tx * 4] =
        make_float4(acc[ii][0], acc[ii][1], acc[ii][2], acc[ii][3]);
}

// ---------------- 3) small bilinears: wku/wvu, ks_sum/vs_sum, nq2/nk2 ----------------
__global__ __launch_bounds__(256) void s1_k(const float* __restrict__ Wq,
                                            const float* __restrict__ Wk,
                                            const float* __restrict__ Wv,
                                            const float* __restrict__ bq,
                                            const float* __restrict__ bk,
                                            const float* __restrict__ bv,
                                            float* __restrict__ ws) {
  const int tid = threadIdx.x;
  const int c = blockIdx.x * 64 + (tid >> 2);
  const int part = tid & 3;
  const int i0 = part * 64;
  const int job = blockIdx.y;
  __shared__ float red[256];
  float np = 0.f;
  if (job < 4) {
    const int b = job;
    const float* ub = ws + o_us + b * 256;
    const float* wkr = Wk + (size_t)c * 256;
    const float* wvr = Wv + (size_t)c * 256;
    const float* pk = ws + o_Pk + (size_t)b * 131072 + c;
    float dku = 0.f, dvu = 0.f, dpk = 0.f;
#pragma unroll 4
    for (int t = 0; t < 16; ++t) {
      const float4 u4 = *(const float4*)&ub[i0 + t * 4];
      dku += dot4(*(const float4*)&wkr[i0 + t * 4], u4);
      dvu += dot4(*(const float4*)&wvr[i0 + t * 4], u4);
    }
    for (int i = i0; i < i0 + 64; ++i) dpk += wkr[i] * pk[(size_t)i * 512];
    dku += __shfl_down(dku, 2); dku += __shfl_down(dku, 1);
    dvu += __shfl_down(dvu, 2); dvu += __shfl_down(dvu, 1);
    dpk += __shfl_down(dpk, 2); dpk += __shfl_down(dpk, 1);
    if (part == 0) {
      ws[o_wku + b * 512 + c] = dku;
      ws[o_wvu + b * 512 + c] = dvu;
      ws[o_kssum + b * 512 + c] = dku + (float)N_ * bk[c];
      ws[o_vssum + b * 512 + c] = dvu + (float)N_ * bv[c];
      np = dpk + 2.f * bk[c] * dku + (float)N_ * bk[c] * bk[c];
    }
    red[tid] = np;
    __syncthreads();
    for (int s = 128; s > 0; s >>= 1) {
      if (tid < s) red[tid] += red[tid + s];
      __syncthreads();
    }
    if (tid == 0) atomicAdd(&ws[o_nrm + 1], red[0]);
  } else {
    const float* uq = ws + o_uq;
    const float* wqr = Wq + (size_t)c * 256;
    const float* pq = ws + o_Pq + c;
    float dqu = 0.f, dpq = 0.f;
#pragma unroll 4
    for (int t = 0; t < 16; ++t)
      dqu += dot4(*(const float4*)&wqr[i0 + t * 4], *(const float4*)&uq[i0 + t * 4]);
    for (int i = i0; i < i0 + 64; ++i) dpq += wqr[i] * pq[(size_t)i * 512];
    dqu += __shfl_down(dqu, 2); dqu += __shfl_down(dqu, 1);
    dpq += __shfl_down(dpq, 2); dpq += __shfl_down(dpq, 1);
    if (part == 0) np = dpq + 2.f * bq[c] * dqu + (float)R_ * bq[c] * bq[c];
    red[tid] = np;
    __syncthreads();
    for (int s = 128; s > 0; s >>= 1) {
      if (tid < s) red[tid] += red[tid + s];
      __syncthreads();
    }
    if (tid == 0) atomicAdd(&ws[o_nrm], red[0]);
  }
}

// ---------------- 4) kv[b,h] = Wk_h (G_b Wv_h^T) + rank-1 terms ----------------
__global__ __launch_bounds__(256) void kv_k(const float* __restrict__ Wk,
                                            const float* __restrict__ bk,
                                            const float* __restrict__ bv,
                                            float* __restrict__ ws) {
  const int bh = blockIdx.x, b = bh >> 3, h = bh & 7;
  const int o0 = blockIdx.y * 1024 + threadIdx.x * 4;
  const int m = o0 >> 6, d0 = o0 & 63;
  const float* pv = ws + o_Pv + (size_t)b * 131072 + h * 64 + d0;
  const float* wk = Wk + (size_t)(h * 64 + m) * 256;
  float acc[4] = {0.f, 0.f, 0.f, 0.f};
  for (int i = 0; i < 256; ++i) {
    const float w = wk[i];
    const float4 p = *(const float4*)&pv[(size_t)i * 512];
    acc[0] += w * p.x; acc[1] += w * p.y; acc[2] += w * p.z; acc[3] += w * p.w;
  }
  const float wkum = ws[o_wku + b * 512 + h * 64 + m];
  const float bkm = bk[h * 64 + m];
  const float* wvup = ws + o_wvu + b * 512 + h * 64 + d0;
  const float* bvp = bv + h * 64 + d0;
  float rr[4];
#pragma unroll
  for (int e = 0; e < 4; ++e)
    rr[e] = acc[e] + wkum * bvp[e] + bkm * wvup[e] + (float)N_ * bkm * bvp[e];
  *(float4*)&ws[o_kv + (size_t)bh * 4096 + (size_t)m * 64 + d0] =
      make_float4(rr[0], rr[1], rr[2], rr[3]);
}

// ---------------- 5) W1bt/w2bt (bf16, K-major) + C1/C2 (fp32), fold s ----------------
// grid (4 b, 256 i), 512 threads
__global__ __launch_bounds__(512) void w1_k(const float* __restrict__ Wq,
                                            const float* __restrict__ bq,
                                            float* __restrict__ ws) {
  const int b = blockIdx.x, i = blockIdx.y;
  const int c = threadIdx.x, h = c >> 6, d = c & 63;
  const float s = 1.f / (sqrtf(ws[o_nrm]) * sqrtf(ws[o_nrm + 1]));
  const float* kvp = ws + o_kv + (size_t)(b * 8 + h) * 4096 + d;
  unsigned short* W1bt = (unsigned short*)(ws + o_W1bt) + (size_t)b * 131072;
  unsigned short* w2bt = (unsigned short*)(ws + o_w2bt) + b * 4096;
  float a = 0.f;
#pragma unroll 4
  for (int m = 0; m < 64; ++m) a += Wq[(size_t)(h * 64 + m) * 256 + i] * kvp[(size_t)m * 64];
  W1bt[(size_t)c * 256 + i] = f2b(s * a);
  if (c < 16) {
    float w = 0.f;
    if (c < 8) {
      const float* ksp = ws + o_kssum + b * 512 + c * 64;
#pragma unroll 4
      for (int m = 0; m < 64; ++m) w += Wq[(size_t)(c * 64 + m) * 256 + i] * ksp[m];
    }
    w2bt[c * 256 + i] = f2b(s * w);
  }
  if (i == 0) {
    float c1 = 0.f;
    for (int m = 0; m < 64; ++m) c1 += bq[h * 64 + m] * kvp[(size_t)m * 64];
    ws[o_C1 + b * 512 + c] = s * c1 + ws[o_vssum + b * 512 + c];
    if (c < 8) {
      float c2 = 0.f;
      const float* ksp = ws + o_kssum + b * 512 + c * 64;
      for (int m = 0; m < 64; ++m) c2 += bq[c * 64 + m] * ksp[m];
      ws[o_C2 + b * 8 + c] = s * c2 + (float)N_;
    }
  }
}

// ---------------- 6) output: num/den via bf16 MFMA + fused epilogue ----------------
// grid (R/64), 256 threads (4 waves). Wave w owns output cols d = w*16.. for ALL 8 heads.
__global__ __launch_bounds__(256) void out_k(const float* __restrict__ X,
                                             const float* __restrict__ ws,
                                             float* __restrict__ out) {
  const int r0 = blockIdx.x * 64;
  const int b = blockIdx.x >> 8;
  const int tid = threadIdx.x;
  const int lane = tid & 63, wv = tid >> 6;
  const int lc = lane & 15;
  const int klb = (lane >> 4) * 16;

  __shared__ __align__(16) unsigned short Xs[64 * 256];
  __shared__ float invden[64][9];
  char* Xb = (char*)Xs;

  {
    const int row = tid >> 2, kq = (tid & 3) * 64;
    const float* src = X + (size_t)(r0 + row) * DIN + kq;
    const int swz = (row & 7) << 4;
#pragma unroll
    for (int g = 0; g < 8; ++g) {
      const float4 v0 = *(const float4*)(src + g * 8);
      const float4 v1 = *(const float4*)(src + g * 8 + 4);
      short8 p;
      p[0] = (short)f2b(v0.x); p[1] = (short)f2b(v0.y);
      p[2] = (short)f2b(v0.z); p[3] = (short)f2b(v0.w);
      p[4] = (short)f2b(v1.x); p[5] = (short)f2b(v1.y);
      p[6] = (short)f2b(v1.z); p[7] = (short)f2b(v1.w);
      *(short8*)(Xb + ((row * 512 + (kq + g * 8) * 2) ^ swz)) = p;
    }
  }
  __syncthreads();

  const char* W1b = (const char*)((const unsigned short*)(ws + o_W1bt) + (size_t)b * 131072);
  const char* w2b = (const char*)((const unsigned short*)(ws + o_w2bt) + b * 4096);

  f32x4 acc[4][8] = {};
  f32x4 acc2[4] = {};
#pragma unroll
  for (int k32 = 0; k32 < 8; ++k32) {
    const int kbyte = k32 * 64;
    short8 a[4];
#pragma unroll
    for (int fi = 0; fi < 4; ++fi) {
      const int row = fi * 16 + lc;
      a[fi] = *(const short8*)(Xb + ((row * 512 + kbyte + klb) ^ ((row & 7) << 4)));
    }
    short8 bb[8];
#pragma unroll
    for (int fj = 0; fj < 8; ++fj) {
      const int cc = fj * 64 + wv * 16 + lc;
      bb[fj] = *(const short8*)(W1b + cc * 512 + kbyte + klb);
    }
    if (wv == 0) {
      const short8 b2 = *(const short8*)(w2b + lc * 512 + kbyte + klb);
#pragma unroll
      for (int fi = 0; fi < 4; ++fi)
        acc2[fi] = __builtin_amdgcn_mfma_f32_16x16x32_bf16(a[fi], b2, acc2[fi], 0, 0, 0);
    }
#pragma unroll
    for (int fi = 0; fi < 4; ++fi)
#pragma unroll
      for (int fj = 0; fj < 8; ++fj)
        acc[fi][fj] = __builtin_amdgcn_mfma_f32_16x16x32_bf16(a[fi], bb[fj], acc[fi][fj], 0, 0, 0);
  }

  if (wv == 0 && lc < 8) {
    const float c2 = ws[o_C2 + b * 8 + lc];
#pragma unroll
    for (int fi = 0; fi < 4; ++fi) {
      const int rb = fi * 16 + (lane >> 4) * 4;
#pragma unroll
      for (int r = 0; r < 4; ++r) invden[rb + r][lc] = 1.f / (acc2[fi][r] + c2);
    }
  }
  __syncthreads();

  const float* C1p = ws + o_C1 + b * 512;
  float cf[8];
#pragma unroll
  for (int fj = 0; fj < 8; ++fj) cf[fj] = C1p[fj * 64 + wv * 16 + lc];

#pragma unroll
  for (int fi = 0; fi < 4; ++fi) {
    const int rb = fi * 16 + (lane >> 4) * 4;
    float o[4] = {0.f, 0.f, 0.f, 0.f};
#pragma unroll
    for (int fj = 0; fj < 8; ++fj)
#pragma unroll
      for (int r = 0; r < 4; ++r)
        o[r] += (acc[fi][fj][r] + cf[fj]) * invden[rb + r][fj];
#pragma unroll
    for (int r = 0; r < 4; ++r)
      out[(size_t)(r0 + rb + r) * 64 + wv * 16 + lc] = o[r] * 0.125f;
  }
}

extern "C" void kernel_launch(void* const* d_in, const int* in_sizes, int n_in,
                              void* d_out, int out_size, void* d_ws, size_t ws_size,
                              hipStream_t stream) {
  const float* Xq = (const float*)d_in[0];
  const float* Xsrc = (const float*)d_in[1];
  const float* Wq = (const float*)d_in[2];
  const float* bq = (const float*)d_in[3];
  const float* Wk = (const float*)d_in[4];
  const float* bk = (const float*)d_in[5];
  const float* Wv = (const float*)d_in[6];
  const float* bv = (const float*)d_in[7];
  float* out = (float*)d_out;
  float* ws = (float*)d_ws;
  if (ws_size < WS_FLOATS * sizeof(float)) return;  // need >= 7.9 MB scratch
  const bool big = ws_size >= BIG_FLOATS * sizeof(float);  // 75 MB fast path

  hipMemsetAsync(ws, 0, ZERO_FLOATS * sizeof(float), stream);
  gram_k<<<dim3(32, 8), 512, 0, stream>>>(Xq, Xsrc, ws, big ? ws + o_part : nullptr);
  if (big) gred_k<<<dim3(64, 6), 256, 0, stream>>>(ws + o_part, ws);
  p_k<<<dim3(8, 4, 9), 256, 0, stream>>>(Wq, Wk, Wv, ws);
  s1_k<<<dim3(8, 5), 256, 0, stream>>>(Wq, Wk, Wv, bq, bk, bv, ws);
  kv_k<<<dim3(32, 4), 256, 0, stream>>>(Wk, bk, bv, ws);
  w1_k<<<dim3(4, 256), 512, 0, stream>>>(Wq, bq, ws);
  out_k<<<dim3(1024), 256, 0, stream>>>(Xq, ws, out);
}